// Round 7
// baseline (150.182 us; speedup 1.0000x reference)
//
#include <hip/hip_runtime.h>
#include <stdint.h>
#include <math.h>

#define NB 8
#define NC 3
#define HG 256
#define WG 256
#define IMG 1024
#define TOPK 256
#define HALF 32
#define PEAK_THRESH 0.95f
#define NEGV (-1e30f)
#define SELCAP 2048        // selected-set capacity (expected nsel ~290)
#define VB_LO 0x3F733334u  // smallest float bits > 0.95f
// value range (0.95,1) spans 0xCCCCC = 838,860 ULPs; >>12 -> ~205 live buckets of 256
#define NBUCK 256
#define BSHIFT 12

#define ROWS_PB 16                 // rows per peaks block
#define GRPS (HG / ROWS_PB)        // 16 row-groups per plane
#define PLANES (NB * NC)           // 24
#define PK_BLOCKS (PLANES * GRPS)  // 384
#define SLOTS 256                  // candidate slots per peaks block (mean ~118)

typedef float f32x4 __attribute__((ext_vector_type(4)));

// ws layout (bytes):
//   [0, 1536)                      : uint32 bcnt[PK_BLOCKS]
//   [4096, 4096+PK_BLOCKS*SLOTS*8) : uint64 bcand[PK_BLOCKS][SLOTS]   (786 KB)
//   then                           : int4 sel[NB*TOPK]  {y1, x1, valid, 0}
#define WS_BCAND_OFF 4096
#define WS_SEL_OFF   (WS_BCAND_OFF + (size_t)PK_BLOCKS * SLOTS * 8)

// ---------------- Kernel 1: 16-row-tile separable 5x5 peak NMS, slot compaction ----------------
// 384 blocks x 256 threads; thread = one column; 20-row halo in registers; no global atomics.
__global__ void __launch_bounds__(256) peaks_kernel(const float* __restrict__ g,
                                                    float* __restrict__ peaks_out,
                                                    uint32_t* __restrict__ bcnt,
                                                    unsigned long long* __restrict__ bcand) {
    __shared__ float vms[ROWS_PB][WG];
    __shared__ unsigned long long lkeys[SLOTS];
    __shared__ uint32_t lcount;

    int blk   = blockIdx.x;
    int grp   = blk & (GRPS - 1);
    int plane = blk >> 4;              // b*NC + c
    int c     = plane % NC;
    int y0    = grp * ROWS_PB;
    int x     = threadIdx.x;

    if (x == 0) lcount = 0;

    const float* gc = g + (size_t)plane * (HG * WG);
    float col[ROWS_PB + 4];
#pragma unroll
    for (int d = 0; d < ROWS_PB + 4; ++d) {
        int yy = y0 - 2 + d;
        col[d] = (yy >= 0 && yy < HG) ? gc[yy * WG + x] : -INFINITY;
    }
    // vertical 5-max per output row (in registers)
#pragma unroll
    for (int r = 0; r < ROWS_PB; ++r)
        vms[r][x] = fmaxf(fmaxf(fmaxf(col[r], col[r + 1]), fmaxf(col[r + 2], col[r + 3])),
                          col[r + 4]);
    __syncthreads();                   // also orders lcount=0 before LDS atomics

#pragma unroll
    for (int r = 0; r < ROWS_PB; ++r) {
        float v = col[r + 2];
        float h = vms[r][x];
        if (x >= 2)      h = fmaxf(h, vms[r][x - 2]);
        if (x >= 1)      h = fmaxf(h, vms[r][x - 1]);
        if (x <= WG - 2) h = fmaxf(h, vms[r][x + 1]);
        if (x <= WG - 3) h = fmaxf(h, vms[r][x + 2]);
        bool peak = (h == v) && (v > PEAK_THRESH);
        __builtin_nontemporal_store(peak ? v : 0.0f,
            &peaks_out[(size_t)plane * (HG * WG) + (y0 + r) * WG + x]);
        if (peak) {
            uint32_t pos = atomicAdd(&lcount, 1u);
            if (pos < SLOTS) {
                int cell = c * (HG * WG) + (y0 + r) * WG + x;
                lkeys[pos] = ((unsigned long long)__float_as_uint(v) << 32) |
                             (uint32_t)(~(uint32_t)cell);
            }
        }
    }
    __syncthreads();
    uint32_t n = min(lcount, (uint32_t)SLOTS);
    if (x == 0) bcnt[blk] = n;
    if ((uint32_t)x < n) bcand[(size_t)blk * SLOTS + x] = lkeys[x];
}

// ---------------- Kernel 2: histogram-select + rank-by-count top-256 (slot scan) ----------------
__device__ __forceinline__ void emit_entry(int b, int kk, int idx, int vld,
                                           float* boxes_out, float* valid_out, int4* sel) {
    int rem = idx & 65535;
    int cy = rem >> 8, cx = rem & 255;
    int x1 = cx - HALF, y1 = cy - HALF;
    float4 bo = make_float4((float)x1, (float)y1, (float)(cx + HALF), (float)(cy + HALF));
    *(float4*)(boxes_out + ((size_t)b * TOPK + kk) * 4) = bo;
    valid_out[b * TOPK + kk] = vld ? 1.0f : 0.0f;
    sel[b * TOPK + kk] = make_int4(y1, x1, vld, 0);
}

#define BLKS_PER_IMG (NC * GRPS)   // 48

__global__ void __launch_bounds__(1024) topk_kernel(const uint32_t* __restrict__ bcnt,
                                                    const unsigned long long* __restrict__ bcand,
                                                    float* __restrict__ boxes_out,
                                                    float* __restrict__ valid_out,
                                                    int4* __restrict__ sel) {
    __shared__ uint32_t hist[NBUCK];
    __shared__ uint32_t scnts[BLKS_PER_IMG];
    __shared__ unsigned long long skeys[SELCAP];
    __shared__ uint32_t sT, scnt;
    int b = blockIdx.x, t = threadIdx.x;

    if (t < NBUCK) hist[t] = 0;
    if (t < BLKS_PER_IMG) scnts[t] = bcnt[b * BLKS_PER_IMG + t];
    if (t == 0) { sT = 0; scnt = 0; }
    __syncthreads();

    const unsigned long long* cb = bcand + (size_t)b * BLKS_PER_IMG * SLOTS;

    // 1) histogram of value bits: bucket = (vb-LO)>>12, ~205 live buckets
    for (int s = t; s < BLKS_PER_IMG * SLOTS; s += 1024) {
        int j = s >> 8, i = s & (SLOTS - 1);
        if ((uint32_t)i < scnts[j]) {
            uint32_t vb = (uint32_t)(cb[(size_t)j * SLOTS + i] >> 32);
            uint32_t bk = (vb - VB_LO) >> BSHIFT;
            if (bk > (NBUCK - 1u)) bk = NBUCK - 1u;
            atomicAdd(&hist[bk], 1u);
        }
    }
    __syncthreads();

    // 2) inclusive suffix sum over NBUCK buckets
    for (int off = 1; off < NBUCK; off <<= 1) {
        uint32_t v = 0;
        if (t < NBUCK) v = hist[t] + ((t + off < NBUCK) ? hist[t + off] : 0u);
        __syncthreads();
        if (t < NBUCK) hist[t] = v;
        __syncthreads();
    }
    // T = max bucket with suffix count >= TOPK (0 if total < TOPK)
    if (t < NBUCK) {
        uint32_t st  = hist[t];
        uint32_t stn = (t < NBUCK - 1) ? hist[t + 1] : 0u;
        if (st >= TOPK && stn < TOPK) sT = (uint32_t)t;
    }
    __syncthreads();
    uint32_t T = sT;

    // 3) compact keys with bucket >= T into LDS
    for (int s = t; s < BLKS_PER_IMG * SLOTS; s += 1024) {
        int j = s >> 8, i = s & (SLOTS - 1);
        if ((uint32_t)i < scnts[j]) {
            unsigned long long key = cb[(size_t)j * SLOTS + i];
            uint32_t vb = (uint32_t)(key >> 32);
            uint32_t bk = (vb - VB_LO) >> BSHIFT;
            if (bk > (NBUCK - 1u)) bk = NBUCK - 1u;
            if (bk >= T) {
                uint32_t p = atomicAdd(&scnt, 1u);
                if (p < SELCAP) skeys[p] = key;
            }
        }
    }
    __syncthreads();
    int nsel = (int)min(scnt, (uint32_t)SELCAP);

    // prefill (only if fewer than TOPK peaks exist — not this input)
    if (nsel < TOPK && t < TOPK)
        emit_entry(b, t, t, 0, boxes_out, valid_out, sel);
    __syncthreads();

    // 4) rank by counting (keys unique -> ranks form a permutation); LDS broadcast reads
    for (int p = t; p < nsel; p += 1024) {
        unsigned long long key = skeys[p];
        int rank = 0;
        for (int i = 0; i < nsel; ++i)
            rank += (skeys[i] > key) ? 1 : 0;
        if (rank < TOPK)
            emit_entry(b, rank, (int)(~(uint32_t)key), 1, boxes_out, valid_out, sel);
    }
}

// ---------------- Kernel 3: ROI crop + 2x2/stride-1 maxpool (65x65 -> 64x64) ----------------
// One block per (b,k,c); thread owns 16 consecutive outputs in one row-pair.
// Nontemporal stores: pooled is write-once; keep L2 for the image re-reads.
__global__ void __launch_bounds__(256) crop_kernel(const float* __restrict__ images,
                                                   const int4* __restrict__ sel,
                                                   float* __restrict__ pooled) {
    int bid = blockIdx.x;           // bk*NC + c
    int bk  = bid / NC;
    int c   = bid - bk * NC;
    int b   = bk >> 8;
    int4 s = sel[bk];
    int y1 = s.x, x1 = s.y, vld = s.z;

    int t  = threadIdx.x;
    int r  = t >> 2;                // output row 0..63
    int jq = (t & 3) << 4;          // col quad start: 0,16,32,48
    int ya = y1 + r, yb = ya + 1;   // max row = 287 < 1024, never bottom-OOB
    const float* img = images + ((size_t)b * NC + c) * (size_t)(IMG * IMG);

    float h[17];
    bool fast = (x1 >= 0 && ya >= 0);
    if (fast) {
        // fully in-image: aligned vector loads + block-uniform window shift
        int c0 = x1 & 3;
        const float* pa = img + (size_t)ya * IMG + ((x1 & ~3) + jq);
        const float* pb = pa + IMG;
        float A[20], B[20];
#pragma unroll
        for (int q = 0; q < 5; ++q) {
            f32x4 a  = *(const f32x4*)(pa + q * 4);
            f32x4 bv = *(const f32x4*)(pb + q * 4);
            A[q * 4 + 0] = a.x;  A[q * 4 + 1] = a.y;  A[q * 4 + 2] = a.z;  A[q * 4 + 3] = a.w;
            B[q * 4 + 0] = bv.x; B[q * 4 + 1] = bv.y; B[q * 4 + 2] = bv.z; B[q * 4 + 3] = bv.w;
        }
#define DO_C0(C0) { _Pragma("unroll") for (int k = 0; k < 17; ++k) h[k] = fmaxf(A[(C0) + k], B[(C0) + k]); }
        switch (c0) {               // block-uniform -> scalar branch, all indices static
            case 0: DO_C0(0); break;
            case 1: DO_C0(1); break;
            case 2: DO_C0(2); break;
            default: DO_C0(3); break;
        }
#undef DO_C0
    } else {
        bool rowa = (ya >= 0), rowb = (yb >= 0);
        const float* ra = img + (size_t)ya * IMG;
        const float* rb = img + (size_t)yb * IMG;
        int xbase = x1 + jq;
#pragma unroll
        for (int k = 0; k < 17; ++k) {
            int xx = xbase + k;
            bool xv = (xx >= 0);
            float va = (rowa && xv) ? ra[xx] : NEGV;
            float vb = (rowb && xv) ? rb[xx] : NEGV;
            h[k] = fmaxf(va, vb);
        }
    }

    float* outp = pooled + (size_t)bid * 4096 + r * 64 + jq;
#pragma unroll
    for (int q = 0; q < 4; ++q) {
        f32x4 o;
#pragma unroll
        for (int e = 0; e < 4; ++e) {
            float mm = fmaxf(h[q * 4 + e], h[q * 4 + e + 1]);
            float rr;
            if (fast) rr = mm;                         // in-image values never hit NEGV
            else      rr = (mm < NEGV * 0.5f) ? 0.0f : mm;
            if (!vld) rr = 0.0f;
            o[e] = rr;
        }
        __builtin_nontemporal_store(o, (f32x4*)(outp + q * 4));
    }
}

extern "C" void kernel_launch(void* const* d_in, const int* in_sizes, int n_in,
                              void* d_out, int out_size, void* d_ws, size_t ws_size,
                              hipStream_t stream) {
    const float* grids  = (const float*)d_in[0];   // [8,3,256,256]
    const float* images = (const float*)d_in[1];   // [8,3,1024,1024]

    float* out = (float*)d_out;
    float* peaks_out = out;                                     // 8*3*256*256 = 1572864
    float* boxes_out = out + (size_t)NB * NC * HG * WG;         // 8*256*4     = 8192
    float* pooled_out = boxes_out + (size_t)NB * TOPK * 4;      // 8*256*3*64*64
    float* valid_out = pooled_out + (size_t)NB * TOPK * NC * 64 * 64;  // 8*256

    uint32_t* bcnt = (uint32_t*)d_ws;
    unsigned long long* bcand = (unsigned long long*)((char*)d_ws + WS_BCAND_OFF);
    int4* sel = (int4*)((char*)d_ws + WS_SEL_OFF);

    peaks_kernel<<<PK_BLOCKS, 256, 0, stream>>>(grids, peaks_out, bcnt, bcand);

    topk_kernel<<<NB, 1024, 0, stream>>>(bcnt, bcand, boxes_out, valid_out, sel);

    crop_kernel<<<NB * TOPK * NC, 256, 0, stream>>>(images, sel, pooled_out);
}

// Round 8
// 63.628 us; speedup vs baseline: 2.3603x; 2.3603x over previous
//
#include <hip/hip_runtime.h>
#include <stdint.h>
#include <math.h>

#define NB 8
#define NC 3
#define HG 256
#define WG 256
#define IMG 1024
#define TOPK 256
#define HALF 32
#define PEAK_THRESH 0.95f
#define NEGV (-1e30f)
#define SELCAP 2048        // selected-set capacity (expected nsel ~290)
#define VB_LO 0x3F733334u  // smallest float bits > 0.95f
// value range (0.95,1) spans 0xCCCCC = 838,860 ULPs; >>12 -> ~205 live buckets of 256
#define NBUCK 256
#define BSHIFT 12

#define ROWS_PB 16                 // rows per peaks block
#define GRPS (HG / ROWS_PB)        // 16 row-groups per plane
#define PLANES (NB * NC)           // 24
#define PK_BLOCKS (PLANES * GRPS)  // 384
#define SLOTS 256                  // candidate slots per peaks block (mean ~118)

typedef float f32x4 __attribute__((ext_vector_type(4)));

// ws layout (bytes):
//   [0, 1536)                      : uint32 bcnt[PK_BLOCKS]
//   [4096, 4096+PK_BLOCKS*SLOTS*8) : uint64 bcand[PK_BLOCKS][SLOTS]   (786 KB)
//   then                           : int4 sel[NB*TOPK]  {y1, x1, valid, 0}
#define WS_BCAND_OFF 4096
#define WS_SEL_OFF   (WS_BCAND_OFF + (size_t)PK_BLOCKS * SLOTS * 8)

// ---------------- Kernel 1: 16-row-tile separable 5x5 peak NMS, slot compaction ----------------
// 384 blocks x 256 threads; thread = one column; 20-row halo in registers; no global atomics.
__global__ void __launch_bounds__(256) peaks_kernel(const float* __restrict__ g,
                                                    float* __restrict__ peaks_out,
                                                    uint32_t* __restrict__ bcnt,
                                                    unsigned long long* __restrict__ bcand) {
    __shared__ float vms[ROWS_PB][WG];
    __shared__ unsigned long long lkeys[SLOTS];
    __shared__ uint32_t lcount;

    int blk   = blockIdx.x;
    int grp   = blk & (GRPS - 1);
    int plane = blk >> 4;              // b*NC + c
    int c     = plane % NC;
    int y0    = grp * ROWS_PB;
    int x     = threadIdx.x;

    if (x == 0) lcount = 0;

    const float* gc = g + (size_t)plane * (HG * WG);
    float col[ROWS_PB + 4];
#pragma unroll
    for (int d = 0; d < ROWS_PB + 4; ++d) {
        int yy = y0 - 2 + d;
        col[d] = (yy >= 0 && yy < HG) ? gc[yy * WG + x] : -INFINITY;
    }
    // vertical 5-max per output row (in registers)
#pragma unroll
    for (int r = 0; r < ROWS_PB; ++r)
        vms[r][x] = fmaxf(fmaxf(fmaxf(col[r], col[r + 1]), fmaxf(col[r + 2], col[r + 3])),
                          col[r + 4]);
    __syncthreads();                   // also orders lcount=0 before LDS atomics

#pragma unroll
    for (int r = 0; r < ROWS_PB; ++r) {
        float v = col[r + 2];
        float h = vms[r][x];
        if (x >= 2)      h = fmaxf(h, vms[r][x - 2]);
        if (x >= 1)      h = fmaxf(h, vms[r][x - 1]);
        if (x <= WG - 2) h = fmaxf(h, vms[r][x + 1]);
        if (x <= WG - 3) h = fmaxf(h, vms[r][x + 2]);
        bool peak = (h == v) && (v > PEAK_THRESH);
        peaks_out[(size_t)plane * (HG * WG) + (y0 + r) * WG + x] = peak ? v : 0.0f;
        if (peak) {
            uint32_t pos = atomicAdd(&lcount, 1u);
            if (pos < SLOTS) {
                int cell = c * (HG * WG) + (y0 + r) * WG + x;
                lkeys[pos] = ((unsigned long long)__float_as_uint(v) << 32) |
                             (uint32_t)(~(uint32_t)cell);
            }
        }
    }
    __syncthreads();
    uint32_t n = min(lcount, (uint32_t)SLOTS);
    if (x == 0) bcnt[blk] = n;
    if ((uint32_t)x < n) bcand[(size_t)blk * SLOTS + x] = lkeys[x];
}

// ---------------- Kernel 2: histogram-select + rank-by-count top-256 (slot scan) ----------------
__device__ __forceinline__ void emit_entry(int b, int kk, int idx, int vld,
                                           float* boxes_out, float* valid_out, int4* sel) {
    int rem = idx & 65535;
    int cy = rem >> 8, cx = rem & 255;
    int x1 = cx - HALF, y1 = cy - HALF;
    float4 bo = make_float4((float)x1, (float)y1, (float)(cx + HALF), (float)(cy + HALF));
    *(float4*)(boxes_out + ((size_t)b * TOPK + kk) * 4) = bo;
    valid_out[b * TOPK + kk] = vld ? 1.0f : 0.0f;
    sel[b * TOPK + kk] = make_int4(y1, x1, vld, 0);
}

#define BLKS_PER_IMG (NC * GRPS)   // 48

__global__ void __launch_bounds__(1024) topk_kernel(const uint32_t* __restrict__ bcnt,
                                                    const unsigned long long* __restrict__ bcand,
                                                    float* __restrict__ boxes_out,
                                                    float* __restrict__ valid_out,
                                                    int4* __restrict__ sel) {
    __shared__ uint32_t hist[NBUCK];
    __shared__ uint32_t scnts[BLKS_PER_IMG];
    __shared__ unsigned long long skeys[SELCAP];
    __shared__ uint32_t sT, scnt;
    int b = blockIdx.x, t = threadIdx.x;

    if (t < NBUCK) hist[t] = 0;
    if (t < BLKS_PER_IMG) scnts[t] = bcnt[b * BLKS_PER_IMG + t];
    if (t == 0) { sT = 0; scnt = 0; }
    __syncthreads();

    const unsigned long long* cb = bcand + (size_t)b * BLKS_PER_IMG * SLOTS;

    // 1) histogram of value bits: bucket = (vb-LO)>>12, ~205 live buckets
    for (int s = t; s < BLKS_PER_IMG * SLOTS; s += 1024) {
        int j = s >> 8, i = s & (SLOTS - 1);
        if ((uint32_t)i < scnts[j]) {
            uint32_t vb = (uint32_t)(cb[(size_t)j * SLOTS + i] >> 32);
            uint32_t bk = (vb - VB_LO) >> BSHIFT;
            if (bk > (NBUCK - 1u)) bk = NBUCK - 1u;
            atomicAdd(&hist[bk], 1u);
        }
    }
    __syncthreads();

    // 2) inclusive suffix sum over NBUCK buckets
    for (int off = 1; off < NBUCK; off <<= 1) {
        uint32_t v = 0;
        if (t < NBUCK) v = hist[t] + ((t + off < NBUCK) ? hist[t + off] : 0u);
        __syncthreads();
        if (t < NBUCK) hist[t] = v;
        __syncthreads();
    }
    // T = max bucket with suffix count >= TOPK (0 if total < TOPK)
    if (t < NBUCK) {
        uint32_t st  = hist[t];
        uint32_t stn = (t < NBUCK - 1) ? hist[t + 1] : 0u;
        if (st >= TOPK && stn < TOPK) sT = (uint32_t)t;
    }
    __syncthreads();
    uint32_t T = sT;

    // 3) compact keys with bucket >= T into LDS
    for (int s = t; s < BLKS_PER_IMG * SLOTS; s += 1024) {
        int j = s >> 8, i = s & (SLOTS - 1);
        if ((uint32_t)i < scnts[j]) {
            unsigned long long key = cb[(size_t)j * SLOTS + i];
            uint32_t vb = (uint32_t)(key >> 32);
            uint32_t bk = (vb - VB_LO) >> BSHIFT;
            if (bk > (NBUCK - 1u)) bk = NBUCK - 1u;
            if (bk >= T) {
                uint32_t p = atomicAdd(&scnt, 1u);
                if (p < SELCAP) skeys[p] = key;
            }
        }
    }
    __syncthreads();
    int nsel = (int)min(scnt, (uint32_t)SELCAP);

    // prefill (only if fewer than TOPK peaks exist — not this input)
    if (nsel < TOPK && t < TOPK)
        emit_entry(b, t, t, 0, boxes_out, valid_out, sel);
    __syncthreads();

    // 4) rank by counting (keys unique -> ranks form a permutation); LDS broadcast reads
    for (int p = t; p < nsel; p += 1024) {
        unsigned long long key = skeys[p];
        int rank = 0;
        for (int i = 0; i < nsel; ++i)
            rank += (skeys[i] > key) ? 1 : 0;
        if (rank < TOPK)
            emit_entry(b, rank, (int)(~(uint32_t)key), 1, boxes_out, valid_out, sel);
    }
}

// ---------------- Kernel 3: ROI crop + 2x2/stride-1 maxpool (65x65 -> 64x64) ----------------
// One block per (b,k,c). Lane-contiguous mapping: thread t owns float4 at linear
// offset t*4 (+ it*1024 per iteration) -> wave stores are 256B-contiguous runs,
// and image loads are consecutive float4s across 16 lanes (full 64B lines).
__global__ void __launch_bounds__(256) crop_kernel(const float* __restrict__ images,
                                                   const int4* __restrict__ sel,
                                                   float* __restrict__ pooled) {
    int bid = blockIdx.x;           // bk*NC + c
    int bk  = bid / NC;
    int c   = bid - bk * NC;
    int b   = bk >> 8;
    int4 s = sel[bk];
    int y1 = s.x, x1 = s.y, vld = s.z;

    int t     = threadIdx.x;
    int j0    = (t & 15) * 4;       // output col start (0,4,..,60)
    int rbase = t >> 4;             // 0..15
    int xa    = x1 & ~3;            // floor to multiple of 4 (works for negatives)
    int c0    = x1 & 3;             // block-uniform window shift
    const float* img  = images + ((size_t)b * NC + c) * (size_t)(IMG * IMG);
    float*       outc = pooled + (size_t)bid * 4096;

#pragma unroll
    for (int it = 0; it < 4; ++it) {
        int r  = it * 16 + rbase;   // output row 0..63
        int ya = y1 + r, yb = ya + 1;   // max row 287 < 1024, right edge max 287 < 1024
        float w[8];                 // max-over-2-rows of image cols xa+j0 .. xa+j0+7
        bool fast = (x1 >= 0 && ya >= 0);
        if (fast) {
            const float* pa = img + (size_t)ya * IMG + (xa + j0);
            const float* pb = pa + IMG;
            f32x4 a0 = *(const f32x4*)pa;
            f32x4 a1 = *(const f32x4*)(pa + 4);
            f32x4 b0 = *(const f32x4*)pb;
            f32x4 b1 = *(const f32x4*)(pb + 4);
#pragma unroll
            for (int e = 0; e < 4; ++e) { w[e] = fmaxf(a0[e], b0[e]); w[e + 4] = fmaxf(a1[e], b1[e]); }
        } else {
            bool rowa = (ya >= 0), rowb = (yb >= 0);
            const float* ra = img + (size_t)ya * IMG;
            const float* rb = img + (size_t)yb * IMG;
#pragma unroll
            for (int k = 0; k < 8; ++k) {
                int xx = xa + j0 + k;
                bool xv = (xx >= 0);
                float va = (rowa && xv) ? ra[xx] : NEGV;
                float vb = (rowb && xv) ? rb[xx] : NEGV;
                w[k] = fmaxf(va, vb);
            }
        }

        f32x4 o;
#define DO_C0(C0) { _Pragma("unroll") for (int e = 0; e < 4; ++e) o[e] = fmaxf(w[(C0) + e], w[(C0) + e + 1]); }
        switch (c0) {               // block-uniform -> scalar branch, all indices static
            case 0: DO_C0(0); break;
            case 1: DO_C0(1); break;
            case 2: DO_C0(2); break;
            default: DO_C0(3); break;
        }
#undef DO_C0
#pragma unroll
        for (int e = 0; e < 4; ++e) {
            float rr = o[e];
            if (!fast) rr = (rr < NEGV * 0.5f) ? 0.0f : rr;   // empty/outside bins -> 0
            if (!vld) rr = 0.0f;
            o[e] = rr;
        }
        *(f32x4*)(outc + r * 64 + j0) = o;
    }
}

extern "C" void kernel_launch(void* const* d_in, const int* in_sizes, int n_in,
                              void* d_out, int out_size, void* d_ws, size_t ws_size,
                              hipStream_t stream) {
    const float* grids  = (const float*)d_in[0];   // [8,3,256,256]
    const float* images = (const float*)d_in[1];   // [8,3,1024,1024]

    float* out = (float*)d_out;
    float* peaks_out = out;                                     // 8*3*256*256 = 1572864
    float* boxes_out = out + (size_t)NB * NC * HG * WG;         // 8*256*4     = 8192
    float* pooled_out = boxes_out + (size_t)NB * TOPK * 4;      // 8*256*3*64*64
    float* valid_out = pooled_out + (size_t)NB * TOPK * NC * 64 * 64;  // 8*256

    uint32_t* bcnt = (uint32_t*)d_ws;
    unsigned long long* bcand = (unsigned long long*)((char*)d_ws + WS_BCAND_OFF);
    int4* sel = (int4*)((char*)d_ws + WS_SEL_OFF);

    peaks_kernel<<<PK_BLOCKS, 256, 0, stream>>>(grids, peaks_out, bcnt, bcand);

    topk_kernel<<<NB, 1024, 0, stream>>>(bcnt, bcand, boxes_out, valid_out, sel);

    crop_kernel<<<NB * TOPK * NC, 256, 0, stream>>>(images, sel, pooled_out);
}